// Round 1
// baseline (584.937 us; speedup 1.0000x reference)
//
#include <hip/hip_runtime.h>
#include <math.h>

#define N_  2
#define L_  512
#define CS  384
#define CZ  128
#define H_  12
#define D_  32
#define HD  384   // H_*D_

__device__ __forceinline__ float sigmoidf_(float x) { return 1.f / (1.f + __expf(-x)); }

// ---------------- K0: LayerNorm of s -> sn [N*L][CS] ----------------
__global__ __launch_bounds__(64) void k_ln_s(const float* __restrict__ s,
        const float* __restrict__ w, const float* __restrict__ b,
        float* __restrict__ sn) {
    int row = blockIdx.x;                 // 0..N*L-1
    const float* x = s + (size_t)row * CS;
    float* y = sn + (size_t)row * CS;
    int lane = threadIdx.x;
    float v[6];
    float sum = 0.f, sq = 0.f;
#pragma unroll
    for (int e = 0; e < 6; ++e) {
        v[e] = x[lane + e * 64];
        sum += v[e];
        sq  += v[e] * v[e];
    }
#pragma unroll
    for (int o = 1; o < 64; o <<= 1) {
        sum += __shfl_xor(sum, o);
        sq  += __shfl_xor(sq , o);
    }
    float m = sum * (1.f / CS);
    float var = sq * (1.f / CS) - m * m;
    float rstd = rsqrtf(var + 1e-5f);
#pragma unroll
    for (int e = 0; e < 6; ++e) {
        int c = lane + e * 64;
        y[c] = (v[e] - m) * rstd * w[c] + b[c];
    }
}

// ---------------- Kw: fold ln_z into wz ----------------
// wzp[h][c] = ln_z_w[c]*wz[h][c];  wzps[h]=sum_c wzp;  wzb[h]=sum_c ln_z_b[c]*wz[h][c]
__global__ __launch_bounds__(128) void k_wz_prep(const float* __restrict__ lnzw,
        const float* __restrict__ lnzb, const float* __restrict__ wz,
        float* __restrict__ wzp, float* __restrict__ wzps, float* __restrict__ wzb) {
    __shared__ float sp[H_][CZ];
    __shared__ float sb[H_][CZ];
    int c = threadIdx.x; // 0..127
    float lw = lnzw[c], lb = lnzb[c];
    for (int h = 0; h < H_; ++h) {
        float w = wz[h * CZ + c];
        float p = lw * w;
        sp[h][c] = p;
        sb[h][c] = lb * w;
        wzp[h * CZ + c] = p;
    }
    __syncthreads();
    if (c < H_) {
        float s1 = 0.f, s2 = 0.f;
        for (int e = 0; e < CZ; ++e) { s1 += sp[c][e]; s2 += sb[c][e]; }
        wzps[c] = s1; wzb[c] = s2;
    }
}

// ---------------- K1: projections q,k,v,gpre = sn x {wq,wk,wv,wg} ----------------
// grid 128 (8 rows each), 384 threads: mat = t/96, 4 cols each, acc[8][4]
__global__ __launch_bounds__(384) void k_proj(const float* __restrict__ sn,
        const float* __restrict__ wq, const float* __restrict__ wk,
        const float* __restrict__ wv, const float* __restrict__ wg,
        float* __restrict__ q, float* __restrict__ k, float* __restrict__ v,
        float* __restrict__ g) {
    __shared__ float s_lds[8][CS];
    int t = threadIdx.x;
    int row0 = blockIdx.x * 8;
    {
        const float4* src = (const float4*)(sn + (size_t)row0 * CS);
        float4* dst = (float4*)(&s_lds[0][0]);
        dst[t] = src[t];
        dst[t + 384] = src[t + 384];
    }
    __syncthreads();
    int mat = t / 96;
    int col = (t % 96) * 4;
    const float* W = (mat == 0) ? wq : (mat == 1) ? wk : (mat == 2) ? wv : wg;
    float acc[8][4];
#pragma unroll
    for (int r = 0; r < 8; ++r)
#pragma unroll
        for (int j = 0; j < 4; ++j) acc[r][j] = 0.f;
    for (int kk = 0; kk < CS; kk += 4) {
        float4 w0 = *(const float4*)(W + (size_t)(kk + 0) * HD + col);
        float4 w1 = *(const float4*)(W + (size_t)(kk + 1) * HD + col);
        float4 w2 = *(const float4*)(W + (size_t)(kk + 2) * HD + col);
        float4 w3 = *(const float4*)(W + (size_t)(kk + 3) * HD + col);
#pragma unroll
        for (int r = 0; r < 8; ++r) {
            float4 sv = *(const float4*)(&s_lds[r][kk]);
            acc[r][0] += sv.x * w0.x + sv.y * w1.x + sv.z * w2.x + sv.w * w3.x;
            acc[r][1] += sv.x * w0.y + sv.y * w1.y + sv.z * w2.y + sv.w * w3.y;
            acc[r][2] += sv.x * w0.z + sv.y * w1.z + sv.z * w2.z + sv.w * w3.z;
            acc[r][3] += sv.x * w0.w + sv.y * w1.w + sv.z * w2.w + sv.w * w3.w;
        }
    }
    float* out = (mat == 0) ? q : (mat == 1) ? k : (mat == 2) ? v : g;
    float scale = (mat == 0) ? 0.17677669529663687f : 1.f;  // 1/sqrt(32) on q
#pragma unroll
    for (int r = 0; r < 8; ++r) {
        float4 o;
        o.x = acc[r][0] * scale; o.y = acc[r][1] * scale;
        o.z = acc[r][2] * scale; o.w = acc[r][3] * scale;
        *(float4*)(out + (size_t)(row0 + r) * HD + col) = o;
    }
}

// ---------------- K2: z -> pair bias [N][H][L][L] (the 256 MB stream) ----------------
// grid (16 jt, 512 i, 2 n), 384 threads. 32 z-rows staged in LDS.
__global__ __launch_bounds__(384) void k_bias(const float* __restrict__ z,
        const float* __restrict__ wzp, const float* __restrict__ wzps,
        const float* __restrict__ wzb, float* __restrict__ bias) {
    __shared__ float z_lds[32][132];
    __shared__ float w_lds[H_][132];
    __shared__ float m_lds[32], r_lds[32];
    __shared__ float ws_lds[H_], wb_lds[H_];
    int t = threadIdx.x;
    int jt = blockIdx.x, i = blockIdx.y, n = blockIdx.z;
    int j0 = jt * 32;
    {   // stage folded weights (L2-hot)
        int h = t >> 5, c4 = t & 31;
        *(float4*)(&w_lds[h][c4 * 4]) = *(const float4*)(wzp + h * CZ + c4 * 4);
        if (t < H_) { ws_lds[t] = wzps[t]; wb_lds[t] = wzb[t]; }
    }
    {   // stage 32 z rows (coalesced float4)
        const float4* src = (const float4*)(z + ((size_t)(n * L_ + i) * L_ + j0) * CZ);
        int idx = t;
        *(float4*)(&z_lds[idx >> 5][(idx & 31) * 4]) = src[idx];
        idx = t + 384;
        *(float4*)(&z_lds[idx >> 5][(idx & 31) * 4]) = src[idx];
        if (t < 256) {
            idx = t + 768;
            *(float4*)(&z_lds[idx >> 5][(idx & 31) * 4]) = src[idx];
        }
    }
    __syncthreads();
    if (t < 256) {  // moments: 8 lanes per row
        int r = t >> 3, lane = t & 7;
        float s1 = 0.f, s2 = 0.f;
#pragma unroll
        for (int e4 = 0; e4 < 4; ++e4) {
            float4 v = *(const float4*)(&z_lds[r][lane * 16 + e4 * 4]);
            s1 += v.x + v.y + v.z + v.w;
            s2 += v.x * v.x + v.y * v.y + v.z * v.z + v.w * v.w;
        }
#pragma unroll
        for (int o = 1; o < 8; o <<= 1) { s1 += __shfl_xor(s1, o); s2 += __shfl_xor(s2, o); }
        if (lane == 0) {
            float m = s1 * (1.f / CZ);
            float var = s2 * (1.f / CZ) - m * m;
            m_lds[r] = m;
            r_lds[r] = rsqrtf(var + 1e-5f);
        }
    }
    __syncthreads();
    int h = t >> 5, j = t & 31;
    float acc = 0.f;
#pragma unroll 8
    for (int c4 = 0; c4 < 32; ++c4) {
        float4 zv = *(const float4*)(&z_lds[j][c4 * 4]);
        float4 wv = *(const float4*)(&w_lds[h][c4 * 4]);
        acc += zv.x * wv.x + zv.y * wv.y + zv.z * wv.z + zv.w * wv.w;
    }
    float bv = r_lds[j] * (acc - m_lds[j] * ws_lds[h]) + wb_lds[h];
    bias[(((size_t)n * H_ + h) * L_ + i) * L_ + j0 + j] = bv;
}

// ---------------- K3: attention per (n,h,16 i-rows); two-pass softmax in LDS ----------------
__global__ __launch_bounds__(256) void k_attn(const float* __restrict__ q,
        const float* __restrict__ k, const float* __restrict__ v,
        const float* __restrict__ gpre, const float* __restrict__ bg,
        const float* __restrict__ bias, float* __restrict__ og) {
    __shared__ float p_lds[16][516];
    __shared__ float k_lds[64][36];
    __shared__ float rinv[16];
    int t = threadIdx.x;
    int it = blockIdx.x, h = blockIdx.y, n = blockIdx.z;
    int i0 = it * 16;
    int i = t >> 4, jsub = t & 15;
    float4 qr[8];
    const float* qrow = q + ((size_t)(n * L_) + i0 + i) * HD + h * D_;
#pragma unroll
    for (int d4 = 0; d4 < 8; ++d4) qr[d4] = *(const float4*)(qrow + d4 * 4);
    const float* bias_row = bias + (((size_t)n * H_ + h) * L_ + i0 + i) * L_;

    for (int s = 0; s < 8; ++s) {
        const float* kbase = k + (size_t)(n * L_ + s * 64) * HD + h * D_;
        {
            int idx = t;
            *(float4*)(&k_lds[idx >> 3][(idx & 7) * 4]) =
                *(const float4*)(kbase + (size_t)(idx >> 3) * HD + (idx & 7) * 4);
            idx = t + 256;
            *(float4*)(&k_lds[idx >> 3][(idx & 7) * 4]) =
                *(const float4*)(kbase + (size_t)(idx >> 3) * HD + (idx & 7) * 4);
        }
        __syncthreads();
        float acc[4];
#pragma unroll
        for (int jj = 0; jj < 4; ++jj) acc[jj] = bias_row[s * 64 + jsub + jj * 16];
#pragma unroll
        for (int d4 = 0; d4 < 8; ++d4) {
            float4 qv = qr[d4];
#pragma unroll
            for (int jj = 0; jj < 4; ++jj) {
                float4 kv = *(const float4*)(&k_lds[jsub + jj * 16][d4 * 4]);
                acc[jj] += qv.x * kv.x + qv.y * kv.y + qv.z * kv.z + qv.w * kv.w;
            }
        }
#pragma unroll
        for (int jj = 0; jj < 4; ++jj) p_lds[i][s * 64 + jsub + jj * 16] = acc[jj];
        __syncthreads();
    }
    // softmax over each row: 16 lanes x 32 elems
    {
        float mx = -1e30f;
#pragma unroll
        for (int e = 0; e < 8; ++e) {
            float4 x = *(const float4*)(&p_lds[i][jsub * 32 + e * 4]);
            mx = fmaxf(mx, fmaxf(fmaxf(x.x, x.y), fmaxf(x.z, x.w)));
        }
#pragma unroll
        for (int o = 1; o < 16; o <<= 1) mx = fmaxf(mx, __shfl_xor(mx, o));
        float sum = 0.f;
#pragma unroll
        for (int e = 0; e < 8; ++e) {
            float4 x = *(const float4*)(&p_lds[i][jsub * 32 + e * 4]);
            x.x = __expf(x.x - mx); x.y = __expf(x.y - mx);
            x.z = __expf(x.z - mx); x.w = __expf(x.w - mx);
            *(float4*)(&p_lds[i][jsub * 32 + e * 4]) = x;
            sum += x.x + x.y + x.z + x.w;
        }
#pragma unroll
        for (int o = 1; o < 16; o <<= 1) sum += __shfl_xor(sum, o);
        if (jsub == 0) rinv[i] = 1.f / sum;
    }
    __syncthreads();
    // PV + gating: thread (i, jsub) owns d = jsub*2, jsub*2+1
    {
        int d = jsub * 2;
        const float* vcol = v + (size_t)(n * L_) * HD + h * D_ + d;
        float o0 = 0.f, o1 = 0.f;
        for (int j = 0; j < L_; ++j) {
            float2 vv = *(const float2*)(vcol + (size_t)j * HD);
            float p = p_lds[i][j];
            o0 += p * vv.x; o1 += p * vv.y;
        }
        float ri = rinv[i];
        o0 *= ri; o1 *= ri;
        size_t gidx = ((size_t)(n * L_) + i0 + i) * HD + h * D_ + d;
        float g0 = sigmoidf_(gpre[gidx]     + bg[h * D_ + d]);
        float g1 = sigmoidf_(gpre[gidx + 1] + bg[h * D_ + d + 1]);
        og[gidx]     = o0 * g0;
        og[gidx + 1] = o1 * g1;
    }
}

// ---------------- K4: out = og x wo + bo ----------------
__global__ __launch_bounds__(384) void k_out(const float* __restrict__ og,
        const float* __restrict__ wo, const float* __restrict__ bo,
        float* __restrict__ out) {
    __shared__ float o_lds[8][HD];
    int t = threadIdx.x;
    int row0 = blockIdx.x * 8;
    {
        const float4* src = (const float4*)(og + (size_t)row0 * HD);
        float4* dst = (float4*)(&o_lds[0][0]);
        dst[t] = src[t];
        dst[t + 384] = src[t + 384];
    }
    __syncthreads();
    float acc[8];
#pragma unroll
    for (int r = 0; r < 8; ++r) acc[r] = 0.f;
    for (int kk = 0; kk < HD; kk += 4) {
        float w0 = wo[(size_t)(kk + 0) * CS + t];
        float w1 = wo[(size_t)(kk + 1) * CS + t];
        float w2 = wo[(size_t)(kk + 2) * CS + t];
        float w3 = wo[(size_t)(kk + 3) * CS + t];
#pragma unroll
        for (int r = 0; r < 8; ++r) {
            float4 ov = *(const float4*)(&o_lds[r][kk]);
            acc[r] += ov.x * w0 + ov.y * w1 + ov.z * w2 + ov.w * w3;
        }
    }
    float bv = bo[t];
#pragma unroll
    for (int r = 0; r < 8; ++r) out[(size_t)(row0 + r) * CS + t] = acc[r] + bv;
}

extern "C" void kernel_launch(void* const* d_in, const int* in_sizes, int n_in,
                              void* d_out, int out_size, void* d_ws, size_t ws_size,
                              hipStream_t stream) {
    const float* s    = (const float*)d_in[0];
    const float* z    = (const float*)d_in[1];
    const float* lnsw = (const float*)d_in[2];
    const float* lnsb = (const float*)d_in[3];
    const float* lnzw = (const float*)d_in[4];
    const float* lnzb = (const float*)d_in[5];
    const float* wz   = (const float*)d_in[6];
    const float* wq   = (const float*)d_in[7];
    const float* wk   = (const float*)d_in[8];
    const float* wv   = (const float*)d_in[9];
    const float* wg   = (const float*)d_in[10];
    const float* bg   = (const float*)d_in[11];
    const float* wo   = (const float*)d_in[12];
    const float* bo   = (const float*)d_in[13];
    float* out = (float*)d_out;

    float* ws = (float*)d_ws;
    const size_t NL = (size_t)N_ * L_;     // 1024
    float* sn   = ws;  ws += NL * CS;
    float* q    = ws;  ws += NL * HD;
    float* kk   = ws;  ws += NL * HD;
    float* vv   = ws;  ws += NL * HD;
    float* gpre = ws;  ws += NL * HD;
    float* og   = ws;  ws += NL * HD;
    float* wzp  = ws;  ws += H_ * CZ;
    float* wzps = ws;  ws += 16;
    float* wzb  = ws;  ws += 16;
    float* bias = ws;  // N_*H_*L_*L_ = 6291456 floats

    k_ln_s<<<dim3(NL), 64, 0, stream>>>(s, lnsw, lnsb, sn);
    k_wz_prep<<<dim3(1), 128, 0, stream>>>(lnzw, lnzb, wz, wzp, wzps, wzb);
    k_proj<<<dim3(128), 384, 0, stream>>>(sn, wq, wk, wv, wg, q, kk, vv, gpre);
    k_bias<<<dim3(16, 512, 2), 384, 0, stream>>>(z, wzp, wzps, wzb, bias);
    k_attn<<<dim3(32, 12, 2), 256, 0, stream>>>(q, kk, vv, gpre, bg, bias, og);
    k_out<<<dim3(128), 384, 0, stream>>>(og, wo, bo, out);
}

// Round 2
// 543.596 us; speedup vs baseline: 1.0761x; 1.0761x over previous
//
#include <hip/hip_runtime.h>
#include <math.h>

#define N_  2
#define L_  512
#define CS  384
#define CZ  128
#define H_  12
#define D_  32
#define HD  384   // H_*D_

__device__ __forceinline__ float sigmoidf_(float x) { return 1.f / (1.f + __expf(-x)); }

// ---------------- K0: LayerNorm of s -> sn [N*L][CS] ----------------
__global__ __launch_bounds__(64) void k_ln_s(const float* __restrict__ s,
        const float* __restrict__ w, const float* __restrict__ b,
        float* __restrict__ sn) {
    int row = blockIdx.x;                 // 0..N*L-1
    const float* x = s + (size_t)row * CS;
    float* y = sn + (size_t)row * CS;
    int lane = threadIdx.x;
    float v[6];
    float sum = 0.f, sq = 0.f;
#pragma unroll
    for (int e = 0; e < 6; ++e) {
        v[e] = x[lane + e * 64];
        sum += v[e];
        sq  += v[e] * v[e];
    }
#pragma unroll
    for (int o = 1; o < 64; o <<= 1) {
        sum += __shfl_xor(sum, o);
        sq  += __shfl_xor(sq , o);
    }
    float m = sum * (1.f / CS);
    float var = sq * (1.f / CS) - m * m;
    float rstd = rsqrtf(var + 1e-5f);
#pragma unroll
    for (int e = 0; e < 6; ++e) {
        int c = lane + e * 64;
        y[c] = (v[e] - m) * rstd * w[c] + b[c];
    }
}

// ---------------- Kw: fold ln_z into wz ----------------
__global__ __launch_bounds__(128) void k_wz_prep(const float* __restrict__ lnzw,
        const float* __restrict__ lnzb, const float* __restrict__ wz,
        float* __restrict__ wzp, float* __restrict__ wzps, float* __restrict__ wzb) {
    __shared__ float sp[H_][CZ];
    __shared__ float sb[H_][CZ];
    int c = threadIdx.x; // 0..127
    float lw = lnzw[c], lb = lnzb[c];
    for (int h = 0; h < H_; ++h) {
        float w = wz[h * CZ + c];
        float p = lw * w;
        sp[h][c] = p;
        sb[h][c] = lb * w;
        wzp[h * CZ + c] = p;
    }
    __syncthreads();
    if (c < H_) {
        float s1 = 0.f, s2 = 0.f;
        for (int e = 0; e < CZ; ++e) { s1 += sp[c][e]; s2 += sb[c][e]; }
        wzps[c] = s1; wzb[c] = s2;
    }
}

// ---------------- K1: projections q,k,v,gpre = sn x {wq,wk,wv,wg} ----------------
__global__ __launch_bounds__(384) void k_proj(const float* __restrict__ sn,
        const float* __restrict__ wq, const float* __restrict__ wk,
        const float* __restrict__ wv, const float* __restrict__ wg,
        float* __restrict__ q, float* __restrict__ k, float* __restrict__ v,
        float* __restrict__ g) {
    __shared__ float s_lds[8][CS];
    int t = threadIdx.x;
    int row0 = blockIdx.x * 8;
    {
        const float4* src = (const float4*)(sn + (size_t)row0 * CS);
        float4* dst = (float4*)(&s_lds[0][0]);
        dst[t] = src[t];
        dst[t + 384] = src[t + 384];
    }
    __syncthreads();
    int mat = t / 96;
    int col = (t % 96) * 4;
    const float* W = (mat == 0) ? wq : (mat == 1) ? wk : (mat == 2) ? wv : wg;
    float acc[8][4];
#pragma unroll
    for (int r = 0; r < 8; ++r)
#pragma unroll
        for (int j = 0; j < 4; ++j) acc[r][j] = 0.f;
    for (int kk = 0; kk < CS; kk += 4) {
        float4 w0 = *(const float4*)(W + (size_t)(kk + 0) * HD + col);
        float4 w1 = *(const float4*)(W + (size_t)(kk + 1) * HD + col);
        float4 w2 = *(const float4*)(W + (size_t)(kk + 2) * HD + col);
        float4 w3 = *(const float4*)(W + (size_t)(kk + 3) * HD + col);
#pragma unroll
        for (int r = 0; r < 8; ++r) {
            float4 sv = *(const float4*)(&s_lds[r][kk]);
            acc[r][0] += sv.x * w0.x + sv.y * w1.x + sv.z * w2.x + sv.w * w3.x;
            acc[r][1] += sv.x * w0.y + sv.y * w1.y + sv.z * w2.y + sv.w * w3.y;
            acc[r][2] += sv.x * w0.z + sv.y * w1.z + sv.z * w2.z + sv.w * w3.z;
            acc[r][3] += sv.x * w0.w + sv.y * w1.w + sv.z * w2.w + sv.w * w3.w;
        }
    }
    float* out = (mat == 0) ? q : (mat == 1) ? k : (mat == 2) ? v : g;
    float scale = (mat == 0) ? 0.17677669529663687f : 1.f;  // 1/sqrt(32) on q
#pragma unroll
    for (int r = 0; r < 8; ++r) {
        float4 o;
        o.x = acc[r][0] * scale; o.y = acc[r][1] * scale;
        o.z = acc[r][2] * scale; o.w = acc[r][3] * scale;
        *(float4*)(out + (size_t)(row0 + r) * HD + col) = o;
    }
}

// ---------------- K2 v2: z -> pair bias, h-tiled (3 head-groups x 32 j x 4 c-slices) ----
__global__ __launch_bounds__(384) void k_bias(const float* __restrict__ z,
        const float* __restrict__ wzp, const float* __restrict__ wzps,
        const float* __restrict__ wzb, float* __restrict__ bias) {
    __shared__ float z_lds[32][132];
    __shared__ float w_lds[H_][132];
    __shared__ float m_lds[32], r_lds[32];
    __shared__ float ws_lds[H_], wb_lds[H_];
    int t = threadIdx.x;
    int jt = blockIdx.x, i = blockIdx.y, n = blockIdx.z;
    int j0 = jt * 32;
    {   // stage folded weights (L2-hot)
        int h = t >> 5, c4 = t & 31;
        *(float4*)(&w_lds[h][c4 * 4]) = *(const float4*)(wzp + h * CZ + c4 * 4);
        if (t < H_) { ws_lds[t] = wzps[t]; wb_lds[t] = wzb[t]; }
    }
    {   // stage 32 z rows (coalesced float4)
        const float4* src = (const float4*)(z + ((size_t)(n * L_ + i) * L_ + j0) * CZ);
        int idx = t;
        *(float4*)(&z_lds[idx >> 5][(idx & 31) * 4]) = src[idx];
        idx = t + 384;
        *(float4*)(&z_lds[idx >> 5][(idx & 31) * 4]) = src[idx];
        if (t < 256) {
            idx = t + 768;
            *(float4*)(&z_lds[idx >> 5][(idx & 31) * 4]) = src[idx];
        }
    }
    __syncthreads();
    if (t < 256) {  // moments: 8 lanes per row
        int r = t >> 3, lane = t & 7;
        float s1 = 0.f, s2 = 0.f;
#pragma unroll
        for (int e4 = 0; e4 < 4; ++e4) {
            float4 v = *(const float4*)(&z_lds[r][lane * 16 + e4 * 4]);
            s1 += v.x + v.y + v.z + v.w;
            s2 += v.x * v.x + v.y * v.y + v.z * v.z + v.w * v.w;
        }
#pragma unroll
        for (int o = 1; o < 8; o <<= 1) { s1 += __shfl_xor(s1, o); s2 += __shfl_xor(s2, o); }
        if (lane == 0) {
            float m = s1 * (1.f / CZ);
            float var = s2 * (1.f / CZ) - m * m;
            m_lds[r] = m;
            r_lds[r] = rsqrtf(var + 1e-5f);
        }
    }
    __syncthreads();
    // dot phase: hg = t>>7 (4 heads), j = (t>>2)&31, cs = t&3 (32-float c-slice)
    int hg = t >> 7;
    int j  = (t >> 2) & 31;
    int cs = t & 3;
    const float* zr = &z_lds[j][cs * 32];
    const float* wr0 = &w_lds[hg * 4 + 0][cs * 32];
    const float* wr1 = &w_lds[hg * 4 + 1][cs * 32];
    const float* wr2 = &w_lds[hg * 4 + 2][cs * 32];
    const float* wr3 = &w_lds[hg * 4 + 3][cs * 32];
    float a0 = 0.f, a1 = 0.f, a2 = 0.f, a3 = 0.f;
#pragma unroll
    for (int e = 0; e < 8; ++e) {
        float4 zv = *(const float4*)(zr + e * 4);
        float4 w0 = *(const float4*)(wr0 + e * 4);
        float4 w1 = *(const float4*)(wr1 + e * 4);
        float4 w2 = *(const float4*)(wr2 + e * 4);
        float4 w3 = *(const float4*)(wr3 + e * 4);
        a0 += zv.x * w0.x + zv.y * w0.y + zv.z * w0.z + zv.w * w0.w;
        a1 += zv.x * w1.x + zv.y * w1.y + zv.z * w1.z + zv.w * w1.w;
        a2 += zv.x * w2.x + zv.y * w2.y + zv.z * w2.z + zv.w * w2.w;
        a3 += zv.x * w3.x + zv.y * w3.y + zv.z * w3.z + zv.w * w3.w;
    }
    // reduce partial dots over the 4 c-slices (cs is in the low 2 lane bits)
    a0 += __shfl_xor(a0, 1); a0 += __shfl_xor(a0, 2);
    a1 += __shfl_xor(a1, 1); a1 += __shfl_xor(a1, 2);
    a2 += __shfl_xor(a2, 1); a2 += __shfl_xor(a2, 2);
    a3 += __shfl_xor(a3, 1); a3 += __shfl_xor(a3, 2);
    // lane cs writes head h = hg*4 + cs
    float dot = (cs == 0) ? a0 : (cs == 1) ? a1 : (cs == 2) ? a2 : a3;
    int hh = hg * 4 + cs;
    float bv = r_lds[j] * (dot - m_lds[j] * ws_lds[hh]) + wb_lds[hh];
    bias[(((size_t)n * H_ + hh) * L_ + i) * L_ + j0 + j] = bv;
}

// ---------------- K3 v2: attention, one wave per (i,h); p in registers ----------------
// block = 512 threads = 8 waves = 8 i-rows of one (n,h). grid (L/8, H, N).
__global__ __launch_bounds__(512) void k_attn(const float* __restrict__ q,
        const float* __restrict__ k, const float* __restrict__ v,
        const float* __restrict__ gpre, const float* __restrict__ bg,
        const float* __restrict__ bias, float* __restrict__ og) {
    __shared__ float t_lds[2][64][36];   // double-buffered 64-row x 32-float tile (+pad)
    int t = threadIdx.x;
    int lane = t & 63;
    int w = t >> 6;
    int it = blockIdx.x, h = blockIdx.y, n = blockIdx.z;
    int i = it * 8 + w;
    int srow = t >> 3, se = t & 7;       // staging: one float4 per thread

    const float* qrow = q + ((size_t)(n * L_) + i) * HD + h * D_;
    float4 qr[8];
#pragma unroll
    for (int d4 = 0; d4 < 8; ++d4) qr[d4] = *(const float4*)(qrow + d4 * 4);
    const float* brow = bias + (((size_t)n * H_ + h) * L_ + i) * L_;
    const float* kbase = k + (size_t)(n * L_) * HD + h * D_;
    const float* vbase = v + (size_t)(n * L_) * HD + h * D_;

    // ---- QK phase ----
    *(float4*)(&t_lds[0][srow][se * 4]) =
        *(const float4*)(kbase + (size_t)srow * HD + se * 4);
    __syncthreads();
    float p[8];
#pragma unroll
    for (int s = 0; s < 8; ++s) {
        float4 stg;
        if (s < 7)
            stg = *(const float4*)(kbase + (size_t)((s + 1) * 64 + srow) * HD + se * 4);
        float acc = brow[s * 64 + lane];
        const float* kr = &t_lds[s & 1][lane][0];
#pragma unroll
        for (int d4 = 0; d4 < 8; ++d4) {
            float4 kv = *(const float4*)(kr + d4 * 4);
            float4 qv = qr[d4];
            acc += qv.x * kv.x + qv.y * kv.y + qv.z * kv.z + qv.w * kv.w;
        }
        p[s] = acc;
        if (s < 7)
            *(float4*)(&t_lds[(s + 1) & 1][srow][se * 4]) = stg;
        __syncthreads();
    }
    // ---- softmax (fully in-wave) ----
    float mx = p[0];
#pragma unroll
    for (int s = 1; s < 8; ++s) mx = fmaxf(mx, p[s]);
#pragma unroll
    for (int o = 1; o < 64; o <<= 1) mx = fmaxf(mx, __shfl_xor(mx, o));
    float sum = 0.f;
#pragma unroll
    for (int s = 0; s < 8; ++s) { p[s] = __expf(p[s] - mx); sum += p[s]; }
#pragma unroll
    for (int o = 1; o < 64; o <<= 1) sum += __shfl_xor(sum, o);
    float rinv = 1.f / sum;

    // ---- PV phase ----
    float acc[32];
#pragma unroll
    for (int d = 0; d < 32; ++d) acc[d] = 0.f;
    *(float4*)(&t_lds[0][srow][se * 4]) =
        *(const float4*)(vbase + (size_t)srow * HD + se * 4);
    __syncthreads();
#pragma unroll
    for (int s = 0; s < 8; ++s) {
        float4 stg;
        if (s < 7)
            stg = *(const float4*)(vbase + (size_t)((s + 1) * 64 + srow) * HD + se * 4);
        float e = p[s];
        const float* vr = &t_lds[s & 1][lane][0];
#pragma unroll
        for (int d4 = 0; d4 < 8; ++d4) {
            float4 vv = *(const float4*)(vr + d4 * 4);
            acc[d4 * 4 + 0] += e * vv.x;
            acc[d4 * 4 + 1] += e * vv.y;
            acc[d4 * 4 + 2] += e * vv.z;
            acc[d4 * 4 + 3] += e * vv.w;
        }
        if (s < 7)
            *(float4*)(&t_lds[(s + 1) & 1][srow][se * 4]) = stg;
        __syncthreads();
    }
    // ---- butterfly-split reduce: 32 accs over 64 lanes -> lane holds d = lane&31 ----
    bool b0 = lane & 1, b1 = lane & 2, b2 = lane & 4, b3 = lane & 8, b4 = lane & 16;
    float r1[16];
#pragma unroll
    for (int m = 0; m < 16; ++m) {
        float give = b0 ? acc[2 * m] : acc[2 * m + 1];
        float got = __shfl_xor(give, 1);
        r1[m] = (b0 ? acc[2 * m + 1] : acc[2 * m]) + got;
    }
    float r2[8];
#pragma unroll
    for (int m = 0; m < 8; ++m) {
        float give = b1 ? r1[2 * m] : r1[2 * m + 1];
        float got = __shfl_xor(give, 2);
        r2[m] = (b1 ? r1[2 * m + 1] : r1[2 * m]) + got;
    }
    float r3[4];
#pragma unroll
    for (int m = 0; m < 4; ++m) {
        float give = b2 ? r2[2 * m] : r2[2 * m + 1];
        float got = __shfl_xor(give, 4);
        r3[m] = (b2 ? r2[2 * m + 1] : r2[2 * m]) + got;
    }
    float r4[2];
#pragma unroll
    for (int m = 0; m < 2; ++m) {
        float give = b3 ? r3[2 * m] : r3[2 * m + 1];
        float got = __shfl_xor(give, 8);
        r4[m] = (b3 ? r3[2 * m + 1] : r3[2 * m]) + got;
    }
    float give = b4 ? r4[0] : r4[1];
    float r5 = (b4 ? r4[1] : r4[0]) + __shfl_xor(give, 16);
    float oval = (r5 + __shfl_xor(r5, 32)) * rinv;

    if (lane < 32) {
        int d = lane;
        size_t gi = ((size_t)(n * L_) + i) * HD + h * D_ + d;
        float g = sigmoidf_(gpre[gi] + bg[h * D_ + d]);
        og[gi] = oval * g;
    }
}

// ---------------- K4: out = og x wo + bo ----------------
__global__ __launch_bounds__(384) void k_out(const float* __restrict__ og,
        const float* __restrict__ wo, const float* __restrict__ bo,
        float* __restrict__ out) {
    __shared__ float o_lds[8][HD];
    int t = threadIdx.x;
    int row0 = blockIdx.x * 8;
    {
        const float4* src = (const float4*)(og + (size_t)row0 * HD);
        float4* dst = (float4*)(&o_lds[0][0]);
        dst[t] = src[t];
        dst[t + 384] = src[t + 384];
    }
    __syncthreads();
    float acc[8];
#pragma unroll
    for (int r = 0; r < 8; ++r) acc[r] = 0.f;
    for (int kk = 0; kk < HD; kk += 4) {
        float w0 = wo[(size_t)(kk + 0) * CS + t];
        float w1 = wo[(size_t)(kk + 1) * CS + t];
        float w2 = wo[(size_t)(kk + 2) * CS + t];
        float w3 = wo[(size_t)(kk + 3) * CS + t];
#pragma unroll
        for (int r = 0; r < 8; ++r) {
            float4 ov = *(const float4*)(&o_lds[r][kk]);
            acc[r] += ov.x * w0 + ov.y * w1 + ov.z * w2 + ov.w * w3;
        }
    }
    float bv = bo[t];
#pragma unroll
    for (int r = 0; r < 8; ++r) out[(size_t)(row0 + r) * CS + t] = acc[r] + bv;
}

extern "C" void kernel_launch(void* const* d_in, const int* in_sizes, int n_in,
                              void* d_out, int out_size, void* d_ws, size_t ws_size,
                              hipStream_t stream) {
    const float* s    = (const float*)d_in[0];
    const float* z    = (const float*)d_in[1];
    const float* lnsw = (const float*)d_in[2];
    const float* lnsb = (const float*)d_in[3];
    const float* lnzw = (const float*)d_in[4];
    const float* lnzb = (const float*)d_in[5];
    const float* wz   = (const float*)d_in[6];
    const float* wq   = (const float*)d_in[7];
    const float* wk   = (const float*)d_in[8];
    const float* wv   = (const float*)d_in[9];
    const float* wg   = (const float*)d_in[10];
    const float* bg   = (const float*)d_in[11];
    const float* wo   = (const float*)d_in[12];
    const float* bo   = (const float*)d_in[13];
    float* out = (float*)d_out;

    float* ws = (float*)d_ws;
    const size_t NL = (size_t)N_ * L_;     // 1024
    float* sn   = ws;  ws += NL * CS;
    float* q    = ws;  ws += NL * HD;
    float* kk   = ws;  ws += NL * HD;
    float* vv   = ws;  ws += NL * HD;
    float* gpre = ws;  ws += NL * HD;
    float* og   = ws;  ws += NL * HD;
    float* wzp  = ws;  ws += H_ * CZ;
    float* wzps = ws;  ws += 16;
    float* wzb  = ws;  ws += 16;
    float* bias = ws;  // N_*H_*L_*L_ = 6291456 floats

    k_ln_s<<<dim3(NL), 64, 0, stream>>>(s, lnsw, lnsb, sn);
    k_wz_prep<<<dim3(1), 128, 0, stream>>>(lnzw, lnzb, wz, wzp, wzps, wzb);
    k_proj<<<dim3(128), 384, 0, stream>>>(sn, wq, wk, wv, wg, q, kk, vv, gpre);
    k_bias<<<dim3(16, 512, 2), 384, 0, stream>>>(z, wzp, wzps, wzb, bias);
    k_attn<<<dim3(64, 12, 2), 512, 0, stream>>>(q, kk, vv, gpre, bg, bias, og);
    k_out<<<dim3(128), 384, 0, stream>>>(og, wo, bo, out);
}